// Round 8
// baseline (5979.264 us; speedup 1.0000x reference)
//
#include <hip/hip_runtime.h>
#include <cstdint>
#include <cstddef>

// Problem constants
#define B_   1024
#define T_   200
#define I_   64
#define H_   512
#define HID_ 256
#define LDA_ 1088   // state row: [h(512) | x_t(64) | c(512)]
#define NFRAG 88    // W frags per j-tile: 4 gates * 18 kk + 16 d kk
#define NGRP 16     // row groups (64 rows each); 2 clusters per block

typedef __bf16 bf16;
typedef __bf16 bf16x4 __attribute__((ext_vector_type(4)));
typedef __bf16 bf16x8 __attribute__((ext_vector_type(8)));
typedef float  f32x4  __attribute__((ext_vector_type(4)));

__device__ inline void gload_lds16(const bf16* g, void* l) {
  void* gg = (void*)g;
  __builtin_amdgcn_global_load_lds((__attribute__((address_space(1))) void*)gg,
                                   (__attribute__((address_space(3))) void*)l,
                                   16, 0, 0);
}

__device__ inline float sigm(float x) { return 1.f / (1.f + __expf(-x)); }
__device__ inline float tanh_f(float x) {
  float e = __expf(2.f * fabsf(x));
  float r = 1.f - 2.f / (e + 1.f);
  return copysignf(r, x);
}
__device__ inline uint32_t bf16bits(float v) {
  union { bf16 h; unsigned short u; } cv; cv.h = (bf16)v; return (uint32_t)cv.u;
}

// ---------------------------------------------------------------------------
// Persistent TimeLSTM, latency-hiding 2-cluster variant.
// 256 blocks x 512 threads (8 waves), 1 block/CU. Block bid = (jt<<3)|mt8:
//   - waves 0-3 = cluster 0 -> group g = mt8*2     (rows g*64 .. +64)
//   - waves 4-7 = cluster 1 -> group g = mt8*2 + 1
// Both clusters compute hidden cols jt*16..+16 and share the block's W LDS
// image (read-only). Clusters are fully independent: NO __syncthreads in the
// loop. While one cluster waits on its group's flags (LLC round-trip), the
// other cluster's waves keep the SIMDs busy -> sync latency is hidden.
//
// Protocol per cluster (r7-proven semantics, per-group):
//  - state writes: agent-scope relaxed atomic stores (coherent at LLC)
//  - publish: each wave drains (vmcnt 0), lane0 bumps LDS arrival counter;
//    the last-arriving wave's lane0 stores flags[g*32+jt] = t+1 (agent atomic)
//  - wait: each wave polls all 32 group flags >= t (agent atomic loads),
//    then fence(acquire, agent) and reads state with normal cached loads.
// Ping-pong safety: flag>=t+1 for all 32 blocks => every reader of buf[t&1]
// (step-t phase C) finished => step t+1 may overwrite buf[t&1].
// ---------------------------------------------------------------------------
__global__ __launch_bounds__(512, 2)
void persist(bf16* __restrict__ ping0, bf16* __restrict__ ping1,
             const float* __restrict__ x, const float* __restrict__ tsT,
             const bf16* __restrict__ img,
             const float* __restrict__ ba, const float* __restrict__ bu,
             const float* __restrict__ bd, int* __restrict__ flags)
{
  __shared__ __align__(16) bf16 Wl[NFRAG * 512];   // 90112 B
  __shared__ int scnt[2];                          // per-cluster arrivals

  const int tid = threadIdx.x;
  const int l   = tid & 63, w = tid >> 6;
  const int cl  = w >> 2, wi = w & 3;
  const int bid = blockIdx.x;
  const int mt8 = bid & 7, jt = bid >> 3;
  const int g   = mt8 * 2 + cl;        // this cluster's row group
  const int m0g = g * 64;              // group row base
  const int m0  = m0g + wi * 16;       // wave's 16-row band
  const int col = l & 15, kh = l >> 4;

  // Load this j-tile's W image (fragment-ordered) into LDS once.
  {
    const bf16* src = img + (size_t)jt * (NFRAG * 512);
#pragma unroll
    for (int it = 0; it < 11; ++it)    // 11 * 8192 B = 90112 B
      gload_lds16(src + it * 4096 + tid * 8, (char*)Wl + it * 8192 + tid * 16);
  }
  if (tid < 2) scnt[tid] = 0;

  float bg[4], bdv;
#pragma unroll
  for (int gg = 0; gg < 4; ++gg) {
    int n = gg * 512 + jt * 16 + col;
    bg[gg] = ba[n] + bu[n];
  }
  bdv = bd[jt * 16 + col];
  __syncthreads();   // drains gload_lds; last block-wide barrier

  float cst[4] = {0.f, 0.f, 0.f, 0.f};   // cell state rows kh*4+q, col
  const bf16x8* Wf = (const bf16x8*)Wl;

  for (int t = 0; t < T_; ++t) {
    const bf16* Ac = (t & 1) ? ping1 : ping0;
    bf16*       An = (t & 1) ? ping0 : ping1;

    // --- phase A: input-only preloads (immutable; overlap the wait) ---
    const int rb = m0 + kh * 4;
    float4 tt4 = *(const float4*)(tsT + (size_t)t * B_ + rb);
    const bool dox = (wi == 0) && (l < 32) && (t + 1 < T_);
    const int xr = m0g + jt * 2 + (l >> 4), xc = (l & 15) * 4;
    float4 xv = {0.f, 0.f, 0.f, 0.f};
    if (dox) xv = *(const float4*)(x + ((size_t)xr * T_ + (t + 1)) * I_ + xc);

    // --- phase B: wait for all 32 group blocks to publish state t ---
    if (t > 0) {
      int* fl = flags + g * 32 + (l & 31);
      while (__hip_atomic_load(fl, __ATOMIC_RELAXED,
                               __HIP_MEMORY_SCOPE_AGENT) < t)
        __builtin_amdgcn_s_sleep(1);
      __builtin_amdgcn_fence(__ATOMIC_ACQUIRE, "agent");  // inv only
    }

    // --- phase C: GEMM (compiler-scheduled; r3/r7-proven loop) ---
    f32x4 acc[4], accd0, accd1;
#pragma unroll
    for (int gg = 0; gg < 4; ++gg) acc[gg] = (f32x4){bg[gg], bg[gg], bg[gg], bg[gg]};
    accd0 = (f32x4){bdv, bdv, bdv, bdv};
    accd1 = (f32x4){0.f, 0.f, 0.f, 0.f};

    const size_t ra = (size_t)(m0 + col) * LDA_ + kh * 8;

    // gates: K = [h(512) | x(64)] -> kk 0..17
#pragma unroll
    for (int kk = 0; kk < 18; ++kk) {
      bf16x8 a = *(const bf16x8*)(Ac + ra + kk * 32);
#pragma unroll
      for (int gg = 0; gg < 4; ++gg) {
        bf16x8 bv = Wf[(gg * 18 + kk) * 64 + l];
        acc[gg] = __builtin_amdgcn_mfma_f32_16x16x32_bf16(a, bv, acc[gg], 0, 0, 0);
      }
    }
    // d: K = c(512) at cols 576..1087 -> kk 0..15, split accumulator
#pragma unroll
    for (int kk = 0; kk < 16; kk += 2) {
      bf16x8 a0 = *(const bf16x8*)(Ac + ra + 576 + kk * 32);
      bf16x8 a1 = *(const bf16x8*)(Ac + ra + 576 + (kk + 1) * 32);
      accd0 = __builtin_amdgcn_mfma_f32_16x16x32_bf16(a0, Wf[(72 + kk) * 64 + l], accd0, 0, 0, 0);
      accd1 = __builtin_amdgcn_mfma_f32_16x16x32_bf16(a1, Wf[(73 + kk) * 64 + l], accd1, 0, 0, 0);
    }

    // --- phase D: gate math + packed agent-atomic state stores ---
#pragma unroll
    for (int q = 0; q < 4; ++q) {
      int row   = rb + q;
      float tt  = (&tt4.x)[q];
      float cs1 = tanh_f(accd0[q] + accd1[q]);
      float cadj = cst[q] - cs1 + cs1 * tt;
      float fg = sigm(acc[0][q]);
      float ig = sigm(acc[1][q]);
      float og = sigm(acc[2][q]);
      float cg_ = sigm(acc[3][q]);
      float cn = fg * cadj + ig * cg_;
      float hn = og * tanh_f(cn);
      cst[q] = cn;

      uint32_t hb = bf16bits(hn), cb = bf16bits(cn);
      uint32_t hb2 = (uint32_t)__shfl_xor((int)hb, 1, 64);
      uint32_t cb2 = (uint32_t)__shfl_xor((int)cb, 1, 64);
      if ((l & 1) == 0) {   // even col owns [col, col+1]
        uint32_t hwd = hb | (hb2 << 16);
        uint32_t cwd = cb | (cb2 << 16);
        uint32_t* hp = (uint32_t*)(An + (size_t)row * LDA_ + jt * 16 + col);
        uint32_t* cp = (uint32_t*)(An + (size_t)row * LDA_ + 576 + jt * 16 + col);
        __hip_atomic_store(hp, hwd, __ATOMIC_RELAXED, __HIP_MEMORY_SCOPE_AGENT);
        __hip_atomic_store(cp, cwd, __ATOMIC_RELAXED, __HIP_MEMORY_SCOPE_AGENT);
      }
    }
    if (dox) {
      union { bf16 h[4]; unsigned long long u; } pk;
      pk.h[0] = (bf16)xv.x; pk.h[1] = (bf16)xv.y;
      pk.h[2] = (bf16)xv.z; pk.h[3] = (bf16)xv.w;
      unsigned long long* xp =
          (unsigned long long*)(An + (size_t)xr * LDA_ + 512 + xc);
      __hip_atomic_store(xp, pk.u, __ATOMIC_RELAXED, __HIP_MEMORY_SCOPE_AGENT);
    }

    // --- phase E: per-cluster publish (no block barrier) ---
    if (t + 1 < T_) {
      asm volatile("s_waitcnt vmcnt(0)" ::: "memory");  // my stores at LLC
      if (l == 0) {
        int prev = atomicAdd(&scnt[cl], 1);             // LDS, workgroup
        if (prev == 4 * (t + 1) - 1)                    // last wave of cluster
          __hip_atomic_store(flags + g * 32 + jt, t + 1, __ATOMIC_RELAXED,
                             __HIP_MEMORY_SCOPE_AGENT);
      }
    }
  }
}

// ---------------------------------------------------------------------------
// Pack W into per-j-tile images in MFMA B-fragment order.
// ---------------------------------------------------------------------------
__global__ void pack_wimg(const float* __restrict__ Wa, const float* __restrict__ Ua,
                          const float* __restrict__ Wd, bf16* __restrict__ img)
{
  int tid = blockIdx.x * 256 + threadIdx.x;   // (jt*88 + f)*64 + lane
  if (tid >= 32 * NFRAG * 64) return;
  int l  = tid & 63;
  int f  = (tid >> 6) % NFRAG;
  int jt = tid / (NFRAG * 64);
  int col = l & 15, kh = l >> 4;
  float v[8];
  if (f < 72) {
    int g = f / 18, kk = f % 18;
    int n = g * 512 + jt * 16 + col;
    if (kk < 16) {
      int k = kk * 32 + kh * 8;
#pragma unroll
      for (int r = 0; r < 8; ++r) v[r] = Wa[(size_t)n * 512 + k + r];
    } else {
      int k = (kk - 16) * 32 + kh * 8;
#pragma unroll
      for (int r = 0; r < 8; ++r) v[r] = Ua[(size_t)n * 64 + k + r];
    }
  } else {
    int kk = f - 72;
    int n = jt * 16 + col;
    int k = kk * 32 + kh * 8;
#pragma unroll
    for (int r = 0; r < 8; ++r) v[r] = Wd[(size_t)n * 512 + k + r];
  }
  bf16* dst = img + (size_t)tid * 8;
#pragma unroll
  for (int r = 0; r < 8; ++r) dst[r] = (bf16)v[r];
}

__global__ void pack_w1(const float* __restrict__ W1, bf16* __restrict__ W1b)
{
  int idx = blockIdx.x * 256 + threadIdx.x;
  if (idx < HID_ * H_) W1b[idx] = (bf16)W1[idx];
}

// init: state (h=0, x=x[:,0,:], c=0), ts transpose, flag zeroing
__global__ void init_state(const float* __restrict__ x, const float* __restrict__ ts,
                           bf16* __restrict__ Acat, float* __restrict__ tsT,
                           int* __restrict__ flags)
{
  int idx = blockIdx.x * 256 + threadIdx.x;
  if (idx < NGRP * 32) flags[idx] = 0;
  if (idx < B_ * T_) {
    int b = idx / T_, t = idx - b * T_;
    tsT[(size_t)t * B_ + b] = ts[idx];
  }
  if (idx >= B_ * LDA_) return;
  int b = idx / LDA_, k = idx - b * LDA_;
  bf16 v = (bf16)0.f;
  if (k >= 512 && k < 576)
    v = (bf16)x[(size_t)b * T_ * I_ + (k - 512)];   // x[:,0,:]
  Acat[idx] = v;
}

// ---------------------------------------------------------------------------
// Tail MLP (round-1-verified gemm + reduce)
// ---------------------------------------------------------------------------
__global__ __launch_bounds__(256)
void gemm_bf16(const bf16* __restrict__ A, int lda,
               const bf16* __restrict__ W, int ldw,
               float* __restrict__ C, int ldc,
               const float* __restrict__ bias,
               int nsplit, int kb0, int ke0, int kb1, int ke1)
{
  __shared__ __align__(16) bf16 As[128 * 64];
  __shared__ __align__(16) bf16 Bs[128 * 64];

  const int tid  = threadIdx.x;
  const int lane = tid & 63;
  const int wave = tid >> 6;
  const int m0 = blockIdx.y * 128;
  const int n0 = blockIdx.x * 128;
  const int kb = (n0 < nsplit) ? kb0 : kb1;
  const int ke = (n0 < nsplit) ? ke0 : ke1;

  int aoff[4], boff[4];
#pragma unroll
  for (int r = 0; r < 4; ++r) {
    int o16 = r * 256 + tid;
    int row = o16 >> 3;
    int sp  = o16 & 7;
    int s   = sp ^ (row & 7);
    aoff[r] = row * lda + s * 8;
    boff[r] = row * ldw + s * 8;
  }

  f32x4 acc[4][4];
#pragma unroll
  for (int i = 0; i < 4; ++i)
#pragma unroll
    for (int j = 0; j < 4; ++j) acc[i][j] = (f32x4){0.f, 0.f, 0.f, 0.f};

  const int wm = wave >> 1, wn = wave & 1;
  const int r15 = lane & 15, khalf = lane >> 4, sw = lane & 7;

  for (int kt = kb; kt < ke; kt += 64) {
    const bf16* Ag = A + (size_t)m0 * lda + kt;
    const bf16* Wg = W + (size_t)n0 * ldw + kt;
#pragma unroll
    for (int r = 0; r < 4; ++r) {
      char* la = (char*)As + (size_t)(r * 256 + wave * 64) * 16;
      char* lb = (char*)Bs + (size_t)(r * 256 + wave * 64) * 16;
      gload_lds16(Ag + aoff[r], la);
      gload_lds16(Wg + boff[r], lb);
    }
    __syncthreads();

    const bf16x8* Ald = (const bf16x8*)As;
    const bf16x8* Bld = (const bf16x8*)Bs;
#pragma unroll
    for (int kk = 0; kk < 2; ++kk) {
      bf16x8 av[4], bv[4];
#pragma unroll
      for (int i = 0; i < 4; ++i) {
        int ra = wm * 64 + i * 16 + r15;
        av[i] = Ald[ra * 8 + ((kk * 4 + khalf) ^ sw)];
        int rbw = wn * 64 + i * 16 + r15;
        bv[i] = Bld[rbw * 8 + ((kk * 4 + khalf) ^ sw)];
      }
#pragma unroll
      for (int i = 0; i < 4; ++i)
#pragma unroll
        for (int j = 0; j < 4; ++j)
          acc[i][j] = __builtin_amdgcn_mfma_f32_16x16x32_bf16(av[i], bv[j], acc[i][j], 0, 0, 0);
    }
    __syncthreads();
  }

#pragma unroll
  for (int j = 0; j < 4; ++j) {
    int colc = n0 + wn * 64 + j * 16 + r15;
    float bb = bias[colc];
#pragma unroll
    for (int i = 0; i < 4; ++i) {
      int rbase = m0 + wm * 64 + i * 16 + khalf * 4;
#pragma unroll
      for (int q = 0; q < 4; ++q)
        C[(size_t)(rbase + q) * ldc + colc] = acc[i][j][q] + bb;
    }
  }
}

__global__ void mlp_out(const float* __restrict__ Gm, const float* __restrict__ W2,
                        const float* __restrict__ b2, float* __restrict__ out)
{
  int b = blockIdx.x, l = threadIdx.x;
  float s = 0.f;
#pragma unroll
  for (int k = l; k < HID_; k += 64)
    s += fmaxf(Gm[(size_t)b * HID_ + k], 0.f) * W2[k];
#pragma unroll
  for (int off = 32; off; off >>= 1) s += __shfl_xor(s, off, 64);
  if (l == 0) out[b] = s + b2[0];
}

// ---------------------------------------------------------------------------
extern "C" void kernel_launch(void* const* d_in, const int* in_sizes, int n_in,
                              void* d_out, int out_size, void* d_ws, size_t ws_size,
                              hipStream_t stream)
{
  const float* x  = (const float*)d_in[0];
  const float* ts = (const float*)d_in[1];
  const float* Wa = (const float*)d_in[2];
  const float* ba = (const float*)d_in[3];
  const float* Ua = (const float*)d_in[4];
  const float* bu = (const float*)d_in[5];
  const float* Wd = (const float*)d_in[6];
  const float* bd = (const float*)d_in[7];
  const float* W1 = (const float*)d_in[8];
  const float* b1 = (const float*)d_in[9];
  const float* W2 = (const float*)d_in[10];
  const float* b2 = (const float*)d_in[11];

  char* ws = (char*)d_ws;
  size_t o = 0;
  auto alloc = [&](size_t bytes) {
    size_t p = o;
    o += (bytes + 255) & ~(size_t)255;
    return p;
  };
  bf16*  Wimg  = (bf16*) (ws + alloc((size_t)32 * NFRAG * 512 * 2));  // 2.88 MB
  bf16*  W1b   = (bf16*) (ws + alloc((size_t)HID_ * H_ * 2));
  bf16*  ping0 = (bf16*) (ws + alloc((size_t)B_ * LDA_ * 2));         // 2.23 MB
  bf16*  ping1 = (bf16*) (ws + alloc((size_t)B_ * LDA_ * 2));
  float* G     = (float*)(ws + alloc((size_t)B_ * HID_ * 4));         // 1 MB
  float* tsT   = (float*)(ws + alloc((size_t)B_ * T_ * 4));           // 0.8 MB
  int*   flags = (int*)  (ws + alloc((size_t)NGRP * 32 * 4));

  pack_wimg<<<(32 * NFRAG * 64 + 255) / 256, 256, 0, stream>>>(Wa, Ua, Wd, Wimg);
  pack_w1<<<(HID_ * H_ + 255) / 256, 256, 0, stream>>>(W1, W1b);
  init_state<<<(B_ * LDA_ + 255) / 256, 256, 0, stream>>>(x, ts, ping0, tsT, flags);

  void* args[] = {(void*)&ping0, (void*)&ping1, (void*)&x, (void*)&tsT,
                  (void*)&Wimg, (void*)&ba, (void*)&bu, (void*)&bd, (void*)&flags};
  hipLaunchCooperativeKernel((void*)persist, dim3(256), dim3(512), args, 0, stream);

  // T=200 even: final state in ping0 (kernel-boundary flush makes it visible)
  gemm_bf16<<<dim3(HID_ / 128, B_ / 128), 256, 0, stream>>>(
      ping0, LDA_, W1b, H_, G, HID_, b1, 1 << 30, 0, 512, 0, 512);
  mlp_out<<<B_, 64, 0, stream>>>(G, W2, b2, (float*)d_out);
}

// Round 9
// 2058.379 us; speedup vs baseline: 2.9048x; 2.9048x over previous
//
#include <hip/hip_runtime.h>
#include <cstdint>
#include <cstddef>

// Problem constants
#define B_   1024
#define T_   200
#define I_   64
#define H_   512
#define HID_ 256
#define LDA_ 1088   // state row: [h(512) | x_t(64) | c(512)]
#define NFRAG 88    // W frags per j-tile: 4 gates * 18 kk + 16 d kk
#define NBUF 12     // state rotation depth (addresses unique for 12 steps)
#define RINV 8      // acquire-inv period; NBUF >= RINV+2 + skew slack

typedef __bf16 bf16;
typedef __bf16 bf16x4 __attribute__((ext_vector_type(4)));
typedef __bf16 bf16x8 __attribute__((ext_vector_type(8)));
typedef float  f32x4  __attribute__((ext_vector_type(4)));

__device__ inline void gload_lds16(const bf16* g, void* l) {
  void* gg = (void*)g;
  __builtin_amdgcn_global_load_lds((__attribute__((address_space(1))) void*)gg,
                                   (__attribute__((address_space(3))) void*)l,
                                   16, 0, 0);
}

__device__ inline float sigm(float x) { return 1.f / (1.f + __expf(-x)); }
__device__ inline float tanh_f(float x) {
  float e = __expf(2.f * fabsf(x));
  float r = 1.f - 2.f / (e + 1.f);
  return copysignf(r, x);
}
__device__ inline uint32_t bf16bits(float v) {
  union { bf16 h; unsigned short u; } cv; cv.h = (bf16)v; return (uint32_t)cv.u;
}

// ---------------------------------------------------------------------------
// Persistent TimeLSTM, r7 protocol + D=12 state rotation, inv every 8 steps.
// 256 blocks x 512 threads (8 waves, 2/SIMD), 1 block/CU.
// Block (mt = bid&7, jt = bid>>3): rows mt*128..+128, hidden cols jt*16..+16.
// W resident in LDS (90KB) for all 200 steps; fp32 cell state in registers.
//
//  - state writes: agent-scope relaxed atomic stores (write-through to LLC)
//  - publish: __syncthreads (vmcnt-drained) then tid0 agent-atomic flag store
//  - wait: wave 0 polls 32 group flags (relaxed agent loads); compiler memory
//    barrier stops load hoisting; fence(acquire,"agent") only when t%8==0
//  - phase-C reads: NORMAL cached loads. Safe because buffer addresses are
//    unique for 12 consecutive steps, group skew <= 1, and every block invs
//    its L1+L2 at least every 8 steps => no cache line can survive from an
//    older step that aliases the current slot.
// ---------------------------------------------------------------------------
__global__ __launch_bounds__(512, 2)
void persist(bf16* __restrict__ states,
             const float* __restrict__ x, const float* __restrict__ tsT,
             const bf16* __restrict__ img,
             const float* __restrict__ ba, const float* __restrict__ bu,
             const float* __restrict__ bd, int* __restrict__ flags)
{
  __shared__ __align__(16) bf16 Wl[NFRAG * 512];   // 90112 B

  const int tid = threadIdx.x;
  const int l   = tid & 63, w = tid >> 6;
  const int bid = blockIdx.x;
  const int mt  = bid & 7, jt = bid >> 3;
  const int m0  = mt * 128;
  const int col = l & 15, kh = l >> 4;
  const size_t SB = (size_t)B_ * LDA_;

  // Load this j-tile's W image (fragment-ordered) into LDS once.
  {
    const bf16* src = img + (size_t)jt * (NFRAG * 512);
#pragma unroll
    for (int it = 0; it < 11; ++it)    // 11 * 8192 B = 90112 B
      gload_lds16(src + it * 4096 + tid * 8, (char*)Wl + it * 8192 + tid * 16);
  }

  float bg[4], bdv;
#pragma unroll
  for (int g = 0; g < 4; ++g) {
    int n = g * 512 + jt * 16 + col;
    bg[g] = ba[n] + bu[n];
  }
  bdv = bd[jt * 16 + col];
  __syncthreads();   // drains gload_lds

  float cst[4] = {0.f, 0.f, 0.f, 0.f};   // cell state for rows kh*4+q, col
  const bf16x8* Wf = (const bf16x8*)Wl;

  int cur = 0, nxt = 1;
  for (int t = 0; t < T_; ++t) {
    const bf16* Ac = states + (size_t)cur * SB;
    bf16*       An = states + (size_t)nxt * SB;

    // --- phase A: input-only preloads (immutable inputs) ---
    const int rb = m0 + w * 16 + kh * 4;
    float4 tt4 = *(const float4*)(tsT + (size_t)t * B_ + rb);
    const bool dox = (tid < 64) && (t + 1 < T_);
    const int xr = m0 + jt * 4 + (tid >> 4), xc = (tid & 15) * 4;
    float4 xv = {0.f, 0.f, 0.f, 0.f};
    if (dox) xv = *(const float4*)(x + ((size_t)xr * T_ + (t + 1)) * I_ + xc);

    // --- phase B: wait for all 32 group blocks to publish state t ---
    if (t > 0) {
      if (w == 0) {
        int* fl = flags + mt * 32 + (l & 31);
        while (__hip_atomic_load(fl, __ATOMIC_RELAXED,
                                 __HIP_MEMORY_SCOPE_AGENT) < t)
          __builtin_amdgcn_s_sleep(1);
        if ((t & (RINV - 1)) == 0)
          __builtin_amdgcn_fence(__ATOMIC_ACQUIRE, "agent");  // periodic inv
        asm volatile("" ::: "memory");   // no load hoisting above the poll
      }
      __syncthreads();
    }

    // --- phase C: GEMM (normal cached loads; rotation makes them safe) ---
    f32x4 acc[4], accd0, accd1;
#pragma unroll
    for (int g = 0; g < 4; ++g) acc[g] = (f32x4){bg[g], bg[g], bg[g], bg[g]};
    accd0 = (f32x4){bdv, bdv, bdv, bdv};
    accd1 = (f32x4){0.f, 0.f, 0.f, 0.f};

    const size_t ra = (size_t)(m0 + w * 16 + col) * LDA_ + kh * 8;

    // gates: K = [h(512) | x(64)] -> kk 0..17
#pragma unroll
    for (int kk = 0; kk < 18; ++kk) {
      bf16x8 a = *(const bf16x8*)(Ac + ra + kk * 32);
#pragma unroll
      for (int g = 0; g < 4; ++g) {
        bf16x8 bv = Wf[(g * 18 + kk) * 64 + l];
        acc[g] = __builtin_amdgcn_mfma_f32_16x16x32_bf16(a, bv, acc[g], 0, 0, 0);
      }
    }
    // d: K = c(512) at cols 576..1087 -> kk 0..15, split accumulator
#pragma unroll
    for (int kk = 0; kk < 16; kk += 2) {
      bf16x8 a0 = *(const bf16x8*)(Ac + ra + 576 + kk * 32);
      bf16x8 a1 = *(const bf16x8*)(Ac + ra + 576 + (kk + 1) * 32);
      accd0 = __builtin_amdgcn_mfma_f32_16x16x32_bf16(a0, Wf[(72 + kk) * 64 + l], accd0, 0, 0, 0);
      accd1 = __builtin_amdgcn_mfma_f32_16x16x32_bf16(a1, Wf[(73 + kk) * 64 + l], accd1, 0, 0, 0);
    }

    // --- phase D: gate math + packed agent-atomic state stores ---
#pragma unroll
    for (int q = 0; q < 4; ++q) {
      int row   = rb + q;
      float tt  = (&tt4.x)[q];
      float cs1 = tanh_f(accd0[q] + accd1[q]);
      float cadj = cst[q] - cs1 + cs1 * tt;
      float fg = sigm(acc[0][q]);
      float ig = sigm(acc[1][q]);
      float og = sigm(acc[2][q]);
      float cg_ = sigm(acc[3][q]);
      float cn = fg * cadj + ig * cg_;
      float hn = og * tanh_f(cn);
      cst[q] = cn;

      uint32_t hb = bf16bits(hn), cb = bf16bits(cn);
      uint32_t hb2 = (uint32_t)__shfl_xor((int)hb, 1, 64);
      uint32_t cb2 = (uint32_t)__shfl_xor((int)cb, 1, 64);
      if ((l & 1) == 0) {   // even col owns [col, col+1]
        uint32_t hwd = hb | (hb2 << 16);
        uint32_t cwd = cb | (cb2 << 16);
        uint32_t* hp = (uint32_t*)(An + (size_t)row * LDA_ + jt * 16 + col);
        uint32_t* cp = (uint32_t*)(An + (size_t)row * LDA_ + 576 + jt * 16 + col);
        __hip_atomic_store(hp, hwd, __ATOMIC_RELAXED, __HIP_MEMORY_SCOPE_AGENT);
        __hip_atomic_store(cp, cwd, __ATOMIC_RELAXED, __HIP_MEMORY_SCOPE_AGENT);
      }
    }
    if (dox) {
      union { bf16 h[4]; unsigned long long u; } pk;
      pk.h[0] = (bf16)xv.x; pk.h[1] = (bf16)xv.y;
      pk.h[2] = (bf16)xv.z; pk.h[3] = (bf16)xv.w;
      unsigned long long* xp =
          (unsigned long long*)(An + (size_t)xr * LDA_ + 512 + xc);
      __hip_atomic_store(xp, pk.u, __ATOMIC_RELAXED, __HIP_MEMORY_SCOPE_AGENT);
    }

    // --- phase E: publish (syncthreads drains every wave's stores first) ---
    if (t + 1 < T_) {
      __syncthreads();
      if (tid == 0)
        __hip_atomic_store(flags + mt * 32 + jt, t + 1, __ATOMIC_RELAXED,
                           __HIP_MEMORY_SCOPE_AGENT);
    }

    cur = nxt;
    nxt = (nxt + 1 == NBUF) ? 0 : nxt + 1;
  }
}

// ---------------------------------------------------------------------------
// Pack W into per-j-tile images in MFMA B-fragment order.
// ---------------------------------------------------------------------------
__global__ void pack_wimg(const float* __restrict__ Wa, const float* __restrict__ Ua,
                          const float* __restrict__ Wd, bf16* __restrict__ img)
{
  int tid = blockIdx.x * 256 + threadIdx.x;   // (jt*88 + f)*64 + lane
  if (tid >= 32 * NFRAG * 64) return;
  int l  = tid & 63;
  int f  = (tid >> 6) % NFRAG;
  int jt = tid / (NFRAG * 64);
  int col = l & 15, kh = l >> 4;
  float v[8];
  if (f < 72) {
    int g = f / 18, kk = f % 18;
    int n = g * 512 + jt * 16 + col;
    if (kk < 16) {
      int k = kk * 32 + kh * 8;
#pragma unroll
      for (int r = 0; r < 8; ++r) v[r] = Wa[(size_t)n * 512 + k + r];
    } else {
      int k = (kk - 16) * 32 + kh * 8;
#pragma unroll
      for (int r = 0; r < 8; ++r) v[r] = Ua[(size_t)n * 64 + k + r];
    }
  } else {
    int kk = f - 72;
    int n = jt * 16 + col;
    int k = kk * 32 + kh * 8;
#pragma unroll
    for (int r = 0; r < 8; ++r) v[r] = Wd[(size_t)n * 512 + k + r];
  }
  bf16* dst = img + (size_t)tid * 8;
#pragma unroll
  for (int r = 0; r < 8; ++r) dst[r] = (bf16)v[r];
}

__global__ void pack_w1(const float* __restrict__ W1, bf16* __restrict__ W1b)
{
  int idx = blockIdx.x * 256 + threadIdx.x;
  if (idx < HID_ * H_) W1b[idx] = (bf16)W1[idx];
}

// init: state buf 0 (h=0, x=x[:,0,:], c=0), ts transpose, flag zeroing
__global__ void init_state(const float* __restrict__ x, const float* __restrict__ ts,
                           bf16* __restrict__ states, float* __restrict__ tsT,
                           int* __restrict__ flags)
{
  int idx = blockIdx.x * 256 + threadIdx.x;
  if (idx < 8 * 32) flags[idx] = 0;
  if (idx < B_ * T_) {
    int b = idx / T_, t = idx - b * T_;
    tsT[(size_t)t * B_ + b] = ts[idx];
  }
  if (idx >= B_ * LDA_) return;
  int b = idx / LDA_, k = idx - b * LDA_;
  bf16 v = (bf16)0.f;
  if (k >= 512 && k < 576)
    v = (bf16)x[(size_t)b * T_ * I_ + (k - 512)];   // x[:,0,:]
  states[idx] = v;
}

// ---------------------------------------------------------------------------
// Tail MLP (round-1-verified gemm + reduce)
// ---------------------------------------------------------------------------
__global__ __launch_bounds__(256)
void gemm_bf16(const bf16* __restrict__ A, int lda,
               const bf16* __restrict__ W, int ldw,
               float* __restrict__ C, int ldc,
               const float* __restrict__ bias,
               int nsplit, int kb0, int ke0, int kb1, int ke1)
{
  __shared__ __align__(16) bf16 As[128 * 64];
  __shared__ __align__(16) bf16 Bs[128 * 64];

  const int tid  = threadIdx.x;
  const int lane = tid & 63;
  const int wave = tid >> 6;
  const int m0 = blockIdx.y * 128;
  const int n0 = blockIdx.x * 128;
  const int kb = (n0 < nsplit) ? kb0 : kb1;
  const int ke = (n0 < nsplit) ? ke0 : ke1;

  int aoff[4], boff[4];
#pragma unroll
  for (int r = 0; r < 4; ++r) {
    int o16 = r * 256 + tid;
    int row = o16 >> 3;
    int sp  = o16 & 7;
    int s   = sp ^ (row & 7);
    aoff[r] = row * lda + s * 8;
    boff[r] = row * ldw + s * 8;
  }

  f32x4 acc[4][4];
#pragma unroll
  for (int i = 0; i < 4; ++i)
#pragma unroll
    for (int j = 0; j < 4; ++j) acc[i][j] = (f32x4){0.f, 0.f, 0.f, 0.f};

  const int wm = wave >> 1, wn = wave & 1;
  const int r15 = lane & 15, khalf = lane >> 4, sw = lane & 7;

  for (int kt = kb; kt < ke; kt += 64) {
    const bf16* Ag = A + (size_t)m0 * lda + kt;
    const bf16* Wg = W + (size_t)n0 * ldw + kt;
#pragma unroll
    for (int r = 0; r < 4; ++r) {
      char* la = (char*)As + (size_t)(r * 256 + wave * 64) * 16;
      char* lb = (char*)Bs + (size_t)(r * 256 + wave * 64) * 16;
      gload_lds16(Ag + aoff[r], la);
      gload_lds16(Wg + boff[r], lb);
    }
    __syncthreads();

    const bf16x8* Ald = (const bf16x8*)As;
    const bf16x8* Bld = (const bf16x8*)Bs;
#pragma unroll
    for (int kk = 0; kk < 2; ++kk) {
      bf16x8 av[4], bv[4];
#pragma unroll
      for (int i = 0; i < 4; ++i) {
        int ra = wm * 64 + i * 16 + r15;
        av[i] = Ald[ra * 8 + ((kk * 4 + khalf) ^ sw)];
        int rbw = wn * 64 + i * 16 + r15;
        bv[i] = Bld[rbw * 8 + ((kk * 4 + khalf) ^ sw)];
      }
#pragma unroll
      for (int i = 0; i < 4; ++i)
#pragma unroll
        for (int j = 0; j < 4; ++j)
          acc[i][j] = __builtin_amdgcn_mfma_f32_16x16x32_bf16(av[i], bv[j], acc[i][j], 0, 0, 0);
    }
    __syncthreads();
  }

#pragma unroll
  for (int j = 0; j < 4; ++j) {
    int colc = n0 + wn * 64 + j * 16 + r15;
    float bb = bias[colc];
#pragma unroll
    for (int i = 0; i < 4; ++i) {
      int rbase = m0 + wm * 64 + i * 16 + khalf * 4;
#pragma unroll
      for (int q = 0; q < 4; ++q)
        C[(size_t)(rbase + q) * ldc + colc] = acc[i][j][q] + bb;
    }
  }
}

__global__ void mlp_out(const float* __restrict__ Gm, const float* __restrict__ W2,
                        const float* __restrict__ b2, float* __restrict__ out)
{
  int b = blockIdx.x, l = threadIdx.x;
  float s = 0.f;
#pragma unroll
  for (int k = l; k < HID_; k += 64)
    s += fmaxf(Gm[(size_t)b * HID_ + k], 0.f) * W2[k];
#pragma unroll
  for (int off = 32; off; off >>= 1) s += __shfl_xor(s, off, 64);
  if (l == 0) out[b] = s + b2[0];
}

// ---------------------------------------------------------------------------
extern "C" void kernel_launch(void* const* d_in, const int* in_sizes, int n_in,
                              void* d_out, int out_size, void* d_ws, size_t ws_size,
                              hipStream_t stream)
{
  const float* x  = (const float*)d_in[0];
  const float* ts = (const float*)d_in[1];
  const float* Wa = (const float*)d_in[2];
  const float* ba = (const float*)d_in[3];
  const float* Ua = (const float*)d_in[4];
  const float* bu = (const float*)d_in[5];
  const float* Wd = (const float*)d_in[6];
  const float* bd = (const float*)d_in[7];
  const float* W1 = (const float*)d_in[8];
  const float* b1 = (const float*)d_in[9];
  const float* W2 = (const float*)d_in[10];
  const float* b2 = (const float*)d_in[11];

  char* ws = (char*)d_ws;
  size_t o = 0;
  auto alloc = [&](size_t bytes) {
    size_t p = o;
    o += (bytes + 255) & ~(size_t)255;
    return p;
  };
  const size_t SB = (size_t)B_ * LDA_;
  bf16*  Wimg   = (bf16*) (ws + alloc((size_t)32 * NFRAG * 512 * 2));  // 2.88 MB
  bf16*  W1b    = (bf16*) (ws + alloc((size_t)HID_ * H_ * 2));
  bf16*  states = (bf16*) (ws + alloc(SB * NBUF * 2));                 // 26.8 MB
  float* G      = (float*)(ws + alloc((size_t)B_ * HID_ * 4));         // 1 MB
  float* tsT    = (float*)(ws + alloc((size_t)B_ * T_ * 4));           // 0.8 MB
  int*   flags  = (int*)  (ws + alloc((size_t)8 * 32 * 4));

  pack_wimg<<<(32 * NFRAG * 64 + 255) / 256, 256, 0, stream>>>(Wa, Ua, Wd, Wimg);
  pack_w1<<<(HID_ * H_ + 255) / 256, 256, 0, stream>>>(W1, W1b);
  init_state<<<(B_ * LDA_ + 255) / 256, 256, 0, stream>>>(x, ts, states, tsT, flags);

  void* args[] = {(void*)&states, (void*)&x, (void*)&tsT,
                  (void*)&Wimg, (void*)&ba, (void*)&bu, (void*)&bd, (void*)&flags};
  hipLaunchCooperativeKernel((void*)persist, dim3(256), dim3(512), args, 0, stream);

  // Final state is in buffer 200 % 12 = 8 (kernel boundary makes it visible)
  gemm_bf16<<<dim3(HID_ / 128, B_ / 128), 256, 0, stream>>>(
      states + 8 * SB, LDA_, W1b, H_, G, HID_, b1, 1 << 30, 0, 512, 0, 512);
  mlp_out<<<B_, 64, 0, stream>>>(G, W2, b2, (float*)d_out);
}

// Round 10
// 2044.759 us; speedup vs baseline: 2.9242x; 1.0067x over previous
//
#include <hip/hip_runtime.h>
#include <cstdint>
#include <cstddef>

// Problem constants
#define B_   1024
#define T_   200
#define I_   64
#define H_   512
#define HID_ 256
#define LDA_ 1088   // state row: [h(512) | x_t(64) | c(512)]
#define NFRAG 88    // W frags per j-tile: 4 gates * 18 kk + 16 d kk
#define NBUF 12     // state rotation depth (addresses unique for 12 steps)
#define RINV 8      // acquire-inv period; NBUF >= RINV+2 + skew slack

typedef __bf16 bf16;
typedef __bf16 bf16x4 __attribute__((ext_vector_type(4)));
typedef __bf16 bf16x8 __attribute__((ext_vector_type(8)));
typedef float  f32x4  __attribute__((ext_vector_type(4)));

__device__ inline void gload_lds16(const bf16* g, void* l) {
  void* gg = (void*)g;
  __builtin_amdgcn_global_load_lds((__attribute__((address_space(1))) void*)gg,
                                   (__attribute__((address_space(3))) void*)l,
                                   16, 0, 0);
}

__device__ inline float sigm(float x) { return 1.f / (1.f + __expf(-x)); }
__device__ inline float tanh_f(float x) {
  float e = __expf(2.f * fabsf(x));
  float r = 1.f - 2.f / (e + 1.f);
  return copysignf(r, x);
}
__device__ inline uint32_t bf16bits(float v) {
  union { bf16 h; unsigned short u; } cv; cv.h = (bf16)v; return (uint32_t)cv.u;
}

// ---------------------------------------------------------------------------
// Persistent TimeLSTM, r9 protocol (rotation D=12, inv every 8 steps)
// + burst register prefetch of the full A row (34 x bf16x8 = 136 VGPR).
// 256 blocks x 512 threads (8 waves, 2/SIMD), 1 block/CU.
// Block (mt = bid&7, jt = bid>>3): rows mt*128..+128, hidden cols jt*16..+16.
// W resident in LDS (90KB) for all 200 steps; fp32 cell state in registers.
// ---------------------------------------------------------------------------
__global__ __launch_bounds__(512, 2)
void persist(bf16* __restrict__ states,
             const float* __restrict__ x, const float* __restrict__ tsT,
             const bf16* __restrict__ img,
             const float* __restrict__ ba, const float* __restrict__ bu,
             const float* __restrict__ bd, int* __restrict__ flags)
{
  __shared__ __align__(16) bf16 Wl[NFRAG * 512];   // 90112 B

  const int tid = threadIdx.x;
  const int l   = tid & 63, w = tid >> 6;
  const int bid = blockIdx.x;
  const int mt  = bid & 7, jt = bid >> 3;
  const int m0  = mt * 128;
  const int col = l & 15, kh = l >> 4;
  const size_t SB = (size_t)B_ * LDA_;

  // Load this j-tile's W image (fragment-ordered) into LDS once.
  {
    const bf16* src = img + (size_t)jt * (NFRAG * 512);
#pragma unroll
    for (int it = 0; it < 11; ++it)    // 11 * 8192 B = 90112 B
      gload_lds16(src + it * 4096 + tid * 8, (char*)Wl + it * 8192 + tid * 16);
  }

  float bg[4], bdv;
#pragma unroll
  for (int g = 0; g < 4; ++g) {
    int n = g * 512 + jt * 16 + col;
    bg[g] = ba[n] + bu[n];
  }
  bdv = bd[jt * 16 + col];
  __syncthreads();   // drains gload_lds

  float cst[4] = {0.f, 0.f, 0.f, 0.f};   // cell state for rows kh*4+q, col
  const bf16x8* Wf = (const bf16x8*)Wl;

  int cur = 0, nxt = 1;
  for (int t = 0; t < T_; ++t) {
    const bf16* Ac = states + (size_t)cur * SB;
    bf16*       An = states + (size_t)nxt * SB;

    // --- phase A: input-only preloads (immutable inputs) ---
    const int rb = m0 + w * 16 + kh * 4;
    float4 tt4 = *(const float4*)(tsT + (size_t)t * B_ + rb);
    const bool dox = (tid < 64) && (t + 1 < T_);
    const int xr = m0 + jt * 4 + (tid >> 4), xc = (tid & 15) * 4;
    float4 xv = {0.f, 0.f, 0.f, 0.f};
    if (dox) xv = *(const float4*)(x + ((size_t)xr * T_ + (t + 1)) * I_ + xc);

    // --- phase B: wait for all 32 group blocks to publish state t ---
    if (t > 0) {
      if (w == 0) {
        int* fl = flags + mt * 32 + (l & 31);
        while (__hip_atomic_load(fl, __ATOMIC_RELAXED,
                                 __HIP_MEMORY_SCOPE_AGENT) < t)
          __builtin_amdgcn_s_sleep(1);
        if ((t & (RINV - 1)) == 0)
          __builtin_amdgcn_fence(__ATOMIC_ACQUIRE, "agent");  // periodic inv
        asm volatile("" ::: "memory");   // no load hoisting above the poll
      }
      __syncthreads();
    }

    // --- phase C: burst-load full A row into registers, then MFMA ---
    const size_t ra = (size_t)(m0 + w * 16 + col) * LDA_ + kh * 8;

    bf16x8 areg[34];
#pragma unroll
    for (int kk = 0; kk < 18; ++kk)
      areg[kk] = *(const bf16x8*)(Ac + ra + kk * 32);
#pragma unroll
    for (int kk = 0; kk < 16; ++kk)
      areg[18 + kk] = *(const bf16x8*)(Ac + ra + 576 + kk * 32);

    f32x4 acc[4], accd0, accd1;
#pragma unroll
    for (int g = 0; g < 4; ++g) acc[g] = (f32x4){bg[g], bg[g], bg[g], bg[g]};
    accd0 = (f32x4){bdv, bdv, bdv, bdv};
    accd1 = (f32x4){0.f, 0.f, 0.f, 0.f};

    // gates: K = [h(512) | x(64)] -> kk 0..17
#pragma unroll
    for (int kk = 0; kk < 18; ++kk) {
#pragma unroll
      for (int g = 0; g < 4; ++g) {
        bf16x8 bv = Wf[(g * 18 + kk) * 64 + l];
        acc[g] = __builtin_amdgcn_mfma_f32_16x16x32_bf16(areg[kk], bv, acc[g], 0, 0, 0);
      }
    }
    // d: K = c(512) -> kk 0..15, split accumulator
#pragma unroll
    for (int kk = 0; kk < 16; kk += 2) {
      accd0 = __builtin_amdgcn_mfma_f32_16x16x32_bf16(areg[18 + kk],     Wf[(72 + kk) * 64 + l], accd0, 0, 0, 0);
      accd1 = __builtin_amdgcn_mfma_f32_16x16x32_bf16(areg[18 + kk + 1], Wf[(73 + kk) * 64 + l], accd1, 0, 0, 0);
    }

    // --- phase D: gate math + packed agent-atomic state stores ---
#pragma unroll
    for (int q = 0; q < 4; ++q) {
      int row   = rb + q;
      float tt  = (&tt4.x)[q];
      float cs1 = tanh_f(accd0[q] + accd1[q]);
      float cadj = cst[q] - cs1 + cs1 * tt;
      float fg = sigm(acc[0][q]);
      float ig = sigm(acc[1][q]);
      float og = sigm(acc[2][q]);
      float cg_ = sigm(acc[3][q]);
      float cn = fg * cadj + ig * cg_;
      float hn = og * tanh_f(cn);
      cst[q] = cn;

      uint32_t hb = bf16bits(hn), cb = bf16bits(cn);
      uint32_t hb2 = (uint32_t)__shfl_xor((int)hb, 1, 64);
      uint32_t cb2 = (uint32_t)__shfl_xor((int)cb, 1, 64);
      if ((l & 1) == 0) {   // even col owns [col, col+1]
        uint32_t hwd = hb | (hb2 << 16);
        uint32_t cwd = cb | (cb2 << 16);
        uint32_t* hp = (uint32_t*)(An + (size_t)row * LDA_ + jt * 16 + col);
        uint32_t* cp = (uint32_t*)(An + (size_t)row * LDA_ + 576 + jt * 16 + col);
        __hip_atomic_store(hp, hwd, __ATOMIC_RELAXED, __HIP_MEMORY_SCOPE_AGENT);
        __hip_atomic_store(cp, cwd, __ATOMIC_RELAXED, __HIP_MEMORY_SCOPE_AGENT);
      }
    }
    if (dox) {
      union { bf16 h[4]; unsigned long long u; } pk;
      pk.h[0] = (bf16)xv.x; pk.h[1] = (bf16)xv.y;
      pk.h[2] = (bf16)xv.z; pk.h[3] = (bf16)xv.w;
      unsigned long long* xp =
          (unsigned long long*)(An + (size_t)xr * LDA_ + 512 + xc);
      __hip_atomic_store(xp, pk.u, __ATOMIC_RELAXED, __HIP_MEMORY_SCOPE_AGENT);
    }

    // --- phase E: publish (syncthreads drains every wave's stores first) ---
    if (t + 1 < T_) {
      __syncthreads();
      if (tid == 0)
        __hip_atomic_store(flags + mt * 32 + jt, t + 1, __ATOMIC_RELAXED,
                           __HIP_MEMORY_SCOPE_AGENT);
    }

    cur = nxt;
    nxt = (nxt + 1 == NBUF) ? 0 : nxt + 1;
  }
}

// ---------------------------------------------------------------------------
// Pack W into per-j-tile images in MFMA B-fragment order.
// ---------------------------------------------------------------------------
__global__ void pack_wimg(const float* __restrict__ Wa, const float* __restrict__ Ua,
                          const float* __restrict__ Wd, bf16* __restrict__ img)
{
  int tid = blockIdx.x * 256 + threadIdx.x;   // (jt*88 + f)*64 + lane
  if (tid >= 32 * NFRAG * 64) return;
  int l  = tid & 63;
  int f  = (tid >> 6) % NFRAG;
  int jt = tid / (NFRAG * 64);
  int col = l & 15, kh = l >> 4;
  float v[8];
  if (f < 72) {
    int g = f / 18, kk = f % 18;
    int n = g * 512 + jt * 16 + col;
    if (kk < 16) {
      int k = kk * 32 + kh * 8;
#pragma unroll
      for (int r = 0; r < 8; ++r) v[r] = Wa[(size_t)n * 512 + k + r];
    } else {
      int k = (kk - 16) * 32 + kh * 8;
#pragma unroll
      for (int r = 0; r < 8; ++r) v[r] = Ua[(size_t)n * 64 + k + r];
    }
  } else {
    int kk = f - 72;
    int n = jt * 16 + col;
    int k = kk * 32 + kh * 8;
#pragma unroll
    for (int r = 0; r < 8; ++r) v[r] = Wd[(size_t)n * 512 + k + r];
  }
  bf16* dst = img + (size_t)tid * 8;
#pragma unroll
  for (int r = 0; r < 8; ++r) dst[r] = (bf16)v[r];
}

__global__ void pack_w1(const float* __restrict__ W1, bf16* __restrict__ W1b)
{
  int idx = blockIdx.x * 256 + threadIdx.x;
  if (idx < HID_ * H_) W1b[idx] = (bf16)W1[idx];
}

// init: state buf 0 (h=0, x=x[:,0,:], c=0), ts transpose, flag zeroing
__global__ void init_state(const float* __restrict__ x, const float* __restrict__ ts,
                           bf16* __restrict__ states, float* __restrict__ tsT,
                           int* __restrict__ flags)
{
  int idx = blockIdx.x * 256 + threadIdx.x;
  if (idx < 8 * 32) flags[idx] = 0;
  if (idx < B_ * T_) {
    int b = idx / T_, t = idx - b * T_;
    tsT[(size_t)t * B_ + b] = ts[idx];
  }
  if (idx >= B_ * LDA_) return;
  int b = idx / LDA_, k = idx - b * LDA_;
  bf16 v = (bf16)0.f;
  if (k >= 512 && k < 576)
    v = (bf16)x[(size_t)b * T_ * I_ + (k - 512)];   // x[:,0,:]
  states[idx] = v;
}

// ---------------------------------------------------------------------------
// Tail MLP (round-1-verified gemm + reduce)
// ---------------------------------------------------------------------------
__global__ __launch_bounds__(256)
void gemm_bf16(const bf16* __restrict__ A, int lda,
               const bf16* __restrict__ W, int ldw,
               float* __restrict__ C, int ldc,
               const float* __restrict__ bias,
               int nsplit, int kb0, int ke0, int kb1, int ke1)
{
  __shared__ __align__(16) bf16 As[128 * 64];
  __shared__ __align__(16) bf16 Bs[128 * 64];

  const int tid  = threadIdx.x;
  const int lane = tid & 63;
  const int wave = tid >> 6;
  const int m0 = blockIdx.y * 128;
  const int n0 = blockIdx.x * 128;
  const int kb = (n0 < nsplit) ? kb0 : kb1;
  const int ke = (n0 < nsplit) ? ke0 : ke1;

  int aoff[4], boff[4];
#pragma unroll
  for (int r = 0; r < 4; ++r) {
    int o16 = r * 256 + tid;
    int row = o16 >> 3;
    int sp  = o16 & 7;
    int s   = sp ^ (row & 7);
    aoff[r] = row * lda + s * 8;
    boff[r] = row * ldw + s * 8;
  }

  f32x4 acc[4][4];
#pragma unroll
  for (int i = 0; i < 4; ++i)
#pragma unroll
    for (int j = 0; j < 4; ++j) acc[i][j] = (f32x4){0.f, 0.f, 0.f, 0.f};

  const int wm = wave >> 1, wn = wave & 1;
  const int r15 = lane & 15, khalf = lane >> 4, sw = lane & 7;

  for (int kt = kb; kt < ke; kt += 64) {
    const bf16* Ag = A + (size_t)m0 * lda + kt;
    const bf16* Wg = W + (size_t)n0 * ldw + kt;
#pragma unroll
    for (int r = 0; r < 4; ++r) {
      char* la = (char*)As + (size_t)(r * 256 + wave * 64) * 16;
      char* lb = (char*)Bs + (size_t)(r * 256 + wave * 64) * 16;
      gload_lds16(Ag + aoff[r], la);
      gload_lds16(Wg + boff[r], lb);
    }
    __syncthreads();

    const bf16x8* Ald = (const bf16x8*)As;
    const bf16x8* Bld = (const bf16x8*)Bs;
#pragma unroll
    for (int kk = 0; kk < 2; ++kk) {
      bf16x8 av[4], bv[4];
#pragma unroll
      for (int i = 0; i < 4; ++i) {
        int ra = wm * 64 + i * 16 + r15;
        av[i] = Ald[ra * 8 + ((kk * 4 + khalf) ^ sw)];
        int rbw = wn * 64 + i * 16 + r15;
        bv[i] = Bld[rbw * 8 + ((kk * 4 + khalf) ^ sw)];
      }
#pragma unroll
      for (int i = 0; i < 4; ++i)
#pragma unroll
        for (int j = 0; j < 4; ++j)
          acc[i][j] = __builtin_amdgcn_mfma_f32_16x16x32_bf16(av[i], bv[j], acc[i][j], 0, 0, 0);
    }
    __syncthreads();
  }

#pragma unroll
  for (int j = 0; j < 4; ++j) {
    int colc = n0 + wn * 64 + j * 16 + r15;
    float bb = bias[colc];
#pragma unroll
    for (int i = 0; i < 4; ++i) {
      int rbase = m0 + wm * 64 + i * 16 + khalf * 4;
#pragma unroll
      for (int q = 0; q < 4; ++q)
        C[(size_t)(rbase + q) * ldc + colc] = acc[i][j][q] + bb;
    }
  }
}

__global__ void mlp_out(const float* __restrict__ Gm, const float* __restrict__ W2,
                        const float* __restrict__ b2, float* __restrict__ out)
{
  int b = blockIdx.x, l = threadIdx.x;
  float s = 0.f;
#pragma unroll
  for (int k = l; k < HID_; k += 64)
    s += fmaxf(Gm[(size_t)b * HID_ + k], 0.f) * W2[k];
#pragma unroll
  for (int off = 32; off; off >>= 1) s += __shfl_xor(s, off, 64);
  if (l == 0) out[b] = s + b2[0];
}

// ---------------------------------------------------------------------------
extern "C" void kernel_launch(void* const* d_in, const int* in_sizes, int n_in,
                              void* d_out, int out_size, void* d_ws, size_t ws_size,
                              hipStream_t stream)
{
  const float* x  = (const float*)d_in[0];
  const float* ts = (const float*)d_in[1];
  const float* Wa = (const float*)d_in[2];
  const float* ba = (const float*)d_in[3];
  const float* Ua = (const float*)d_in[4];
  const float* bu = (const float*)d_in[5];
  const float* Wd = (const float*)d_in[6];
  const float* bd = (const float*)d_in[7];
  const float* W1 = (const float*)d_in[8];
  const float* b1 = (const float*)d_in[9];
  const float* W2 = (const float*)d_in[10];
  const float* b2 = (const float*)d_in[11];

  char* ws = (char*)d_ws;
  size_t o = 0;
  auto alloc = [&](size_t bytes) {
    size_t p = o;
    o += (bytes + 255) & ~(size_t)255;
    return p;
  };
  const size_t SB = (size_t)B_ * LDA_;
  bf16*  Wimg   = (bf16*) (ws + alloc((size_t)32 * NFRAG * 512 * 2));  // 2.88 MB
  bf16*  W1b    = (bf16*) (ws + alloc((size_t)HID_ * H_ * 2));
  bf16*  states = (bf16*) (ws + alloc(SB * NBUF * 2));                 // 26.8 MB
  float* G      = (float*)(ws + alloc((size_t)B_ * HID_ * 4));         // 1 MB
  float* tsT    = (float*)(ws + alloc((size_t)B_ * T_ * 4));           // 0.8 MB
  int*   flags  = (int*)  (ws + alloc((size_t)8 * 32 * 4));

  pack_wimg<<<(32 * NFRAG * 64 + 255) / 256, 256, 0, stream>>>(Wa, Ua, Wd, Wimg);
  pack_w1<<<(HID_ * H_ + 255) / 256, 256, 0, stream>>>(W1, W1b);
  init_state<<<(B_ * LDA_ + 255) / 256, 256, 0, stream>>>(x, ts, states, tsT, flags);

  void* args[] = {(void*)&states, (void*)&x, (void*)&tsT,
                  (void*)&Wimg, (void*)&ba, (void*)&bu, (void*)&bd, (void*)&flags};
  hipLaunchCooperativeKernel((void*)persist, dim3(256), dim3(512), args, 0, stream);

  // Final state is in buffer 200 % 12 = 8 (kernel boundary makes it visible)
  gemm_bf16<<<dim3(HID_ / 128, B_ / 128), 256, 0, stream>>>(
      states + 8 * SB, LDA_, W1b, H_, G, HID_, b1, 1 << 30, 0, 512, 0, 512);
  mlp_out<<<B_, 64, 0, stream>>>(G, W2, b2, (float*)d_out);
}